// Round 8
// baseline (1591.147 us; speedup 1.0000x reference)
//
#include <hip/hip_runtime.h>
#include <hip/hip_bf16.h>

// EncoderAttention4 v9: v8's 4-independent-blocks/CU goal, spills engineered out.
// B=65536, NEGO=48, NADO=24, NADOAG=5, E=256, H=4, AD=64. Out: (B,112) fp32.
//
// v8 post-mortem: WRITE 3.3GB / FETCH 1.7GB = scratch spill traffic. The
// allocator pins a 64-VGPR budget under (...,4) launch bounds and spills the
// overflow; v8's wave-per-head state (slct[4], agg[4], kacc[5][2]) blew past
// it -> spill reloads inside MFMA loops -> 3.3x regression. The v5-v7
// WRITE_SIZE creep (230->389MB) was the same effect in miniature.
// v9 changes vs v8:
//  - phase 8 agent-grouped (3+2): simultaneous acc 40->24 regs, af 20->12;
//    same LDS read count (af was already per-pair); +64 L2 B-loads/wave.
//  - __launch_bounds__(256) + amdgpu_waves_per_eu(4,4): 128-reg budget,
//    natural demand now ~60-70V + 24-48 acc -> no spills.
//  - everything else (40KB pool, in-place ado, wave-per-head) as v8.

typedef __bf16 bf16x8 __attribute__((ext_vector_type(8)));
typedef __bf16 bf16x4 __attribute__((ext_vector_type(4)));
typedef float  f32x4  __attribute__((ext_vector_type(4)));

// Workspace layout (bf16 elements), unchanged.
#define OFF_EGO0 0        // [256][64]  (K=48 padded to 64)
#define OFF_EGO1 16384    // [256][256]
#define OFF_ADO0 81920    // [256][32]  (K=25 padded to 32)
#define OFF_ADO1 90112    // [256][256]
#define OFF_SEL  155648   // [256][256] col c -> head c>>6, d c&63
#define OFF_KEY  221184
#define OFF_LAT  286720
#define OFF_PROJ 352256   // [64][256]
#define WS_ELEMS 368640

__global__ __launch_bounds__(256) void prep_weights(
    const float* __restrict__ ew0, const float* __restrict__ ew1,
    const float* __restrict__ aw0, const float* __restrict__ aw1,
    const float* __restrict__ keyw, const float* __restrict__ selw,
    const float* __restrict__ latw, const float* __restrict__ projw,
    __bf16* __restrict__ ws)
{
  int i = blockIdx.x * 256 + threadIdx.x;
  if (i >= WS_ELEMS) return;
  float v;
  if (i < OFF_EGO1)      { int j=i;          int c=j>>6, k=j&63;  v = (k<48) ? ew0[k*256+c] : 0.f; }
  else if (i < OFF_ADO0) { int j=i-OFF_EGO1; int c=j>>8, k=j&255; v = ew1[k*256+c]; }
  else if (i < OFF_ADO1) { int j=i-OFF_ADO0; int c=j>>5, k=j&31;  v = (k<25) ? aw0[k*256+c] : 0.f; }
  else if (i < OFF_SEL)  { int j=i-OFF_ADO1; int c=j>>8, k=j&255; v = aw1[k*256+c]; }
  else if (i < OFF_KEY)  { int j=i-OFF_SEL;  int c=j>>8, k=j&255; v = selw[(c>>6)*16384 + k*64 + (c&63)]; }
  else if (i < OFF_LAT)  { int j=i-OFF_KEY;  int c=j>>8, k=j&255; v = keyw[(c>>6)*16384 + k*64 + (c&63)]; }
  else if (i < OFF_PROJ) { int j=i-OFF_LAT;  int c=j>>8, k=j&255; v = latw[(c>>6)*16384 + k*64 + (c&63)]; }
  else                   { int j=i-OFF_PROJ; int c=j>>8, k=j&255; v = projw[k*64+c]; }
  ws[i] = (__bf16)v;
}

// XOR-swizzled LDS accessors. byte ^= (row&7)<<4 (bijective per 8-row group).
__device__ __forceinline__ bf16x8 lds_loadA(const __bf16* base, int row, int kByte, int rowBytes) {
  int off = (row * rowBytes + kByte) ^ ((row & 7) << 4);
  return *reinterpret_cast<const bf16x8*>(reinterpret_cast<const char*>(base) + off);
}
__device__ __forceinline__ void lds_store_bf16(__bf16* base, int row, int col, __bf16 v) {
  int off = (row * 512 + col * 2) ^ ((row & 7) << 4);  // 256-col tiles only
  *reinterpret_cast<__bf16*>(reinterpret_cast<char*>(base) + off) = v;
}

// LDS pool: exactly 40960B = sAdo2's 80 rows x 512B, aliased lifetimes:
//   EgoIn  rows 0-3    [0,2048)      dead after ego0
//   EgoH1  rows 4-19   [2048,10240)  dead after ego1
//   ObsF   rows 21-41  [10752,21504) dead after input build
//   EgoH2  rows 42-57  [21504,29696) dead after sel (sel BEFORE ado0)
//   AdoIn  rows 58-67  [29696,34816) dead after ado0's reg-held af load
//   sAdo2  rows 0-79                 live ado0 -> lat
//   sProj  rows 0-15   [0,8192)      after attention (barrier)
//   sOutF  rows 16-23  [8192,12288)  fp32 proj output staging
#define P_EGOIN  0
#define P_EGOH1  2048
#define P_OBSRAW 10752
#define P_EGOH2  21504
#define P_ADOIN  29696
#define P_PROJIN 0
#define P_OUTF   8192
#define POOL_BYTES 40960   // 40KB * 4 = 160KB exactly -> 4 blocks/CU

// C(16R rows x 64 cols/wave) = lrelu(A @ WT^T + bias). Wave w owns cols
// w*64 + ct*16 + lr, ct=0..3. SYNCW: barrier between all A-reads and the
// C-writes -> safe when sA and sC ranges overlap (in-place).
template<int KP, int R, bool SYNCW>
__device__ __forceinline__ void gemm4(const __bf16* __restrict__ sA, int aRow0,
                                      __bf16* __restrict__ sC, int cRow0,
                                      const __bf16* __restrict__ WT,
                                      const float* __restrict__ bias,
                                      int w, int lr, int lg)
{
  constexpr int NKB = KP / 32;
  f32x4 acc[R][4];
  #pragma unroll
  for (int t = 0; t < R; ++t)
    #pragma unroll
    for (int ct = 0; ct < 4; ++ct) acc[t][ct] = f32x4{0.f,0.f,0.f,0.f};
  #pragma unroll
  for (int kb = 0; kb < NKB; ++kb) {
    bf16x8 af[R];
    #pragma unroll
    for (int t = 0; t < R; ++t)
      af[t] = lds_loadA(sA, aRow0 + t*16 + lr, kb*64 + lg*16, KP*2);
    #pragma unroll
    for (int ct = 0; ct < 4; ++ct) {
      const int col = w*64 + ct*16 + lr;
      bf16x8 bfr = *reinterpret_cast<const bf16x8*>(WT + col*KP + kb*32 + lg*8);
      #pragma unroll
      for (int t = 0; t < R; ++t)
        acc[t][ct] = __builtin_amdgcn_mfma_f32_16x16x32_bf16(af[t], bfr, acc[t][ct], 0, 0, 0);
    }
  }
  if (SYNCW) __syncthreads();
  #pragma unroll
  for (int ct = 0; ct < 4; ++ct) {
    const int col = w*64 + ct*16 + lr;
    const float bv = bias[col];
    #pragma unroll
    for (int t = 0; t < R; ++t) {
      #pragma unroll
      for (int e = 0; e < 4; ++e) {
        float x = acc[t][ct][e] + bv;
        x = x > 0.f ? x : 0.01f * x;
        lds_store_bf16(sC, cRow0 + t*16 + lg*4 + e, col, (__bf16)x);
      }
    }
  }
}

// Agent-group pass for key/lat: NG agents starting at row base*16 in sAdo2.
// acc[NG][2] per ct-pair; fold is done by the caller.
template<int NG>
__device__ __forceinline__ void attn_group(const __bf16* __restrict__ sAdo2,
                                           const __bf16* __restrict__ WT,
                                           int base, int pair,
                                           int w, int lr, int lg,
                                           f32x4 (&acc)[NG][2])
{
  #pragma unroll
  for (int n = 0; n < NG; ++n) {
    acc[n][0] = f32x4{0.f,0.f,0.f,0.f};
    acc[n][1] = f32x4{0.f,0.f,0.f,0.f};
  }
  #pragma unroll
  for (int kb = 0; kb < 8; ++kb) {
    bf16x8 af[NG];
    #pragma unroll
    for (int n = 0; n < NG; ++n)
      af[n] = lds_loadA(sAdo2, (base + n)*16 + lr, kb*64 + lg*16, 512);
    #pragma unroll
    for (int c2 = 0; c2 < 2; ++c2) {
      const int col = w*64 + (pair*2 + c2)*16 + lr;
      bf16x8 b = *reinterpret_cast<const bf16x8*>(WT + col*256 + kb*32 + lg*8);
      #pragma unroll
      for (int n = 0; n < NG; ++n)
        acc[n][c2] = __builtin_amdgcn_mfma_f32_16x16x32_bf16(af[n], b, acc[n][c2], 0, 0, 0);
    }
  }
}

__global__ __launch_bounds__(256)
__attribute__((amdgpu_waves_per_eu(4, 4)))
void fused_kernel(
    const float* __restrict__ obs,
    const float* __restrict__ eb0, const float* __restrict__ eb1,
    const float* __restrict__ ab0, const float* __restrict__ ab1,
    const float* __restrict__ latb, const float* __restrict__ projb,
    const __bf16* __restrict__ ws,
    float* __restrict__ out)
{
  const int tid = threadIdx.x;
  const int w  = tid >> 6;   // 4 waves; wave = head
  const int l  = tid & 63;
  const int lr = l & 15;
  const int lg = l >> 4;
  const int b0 = blockIdx.x * 16;

  __shared__ __align__(16) char pool[POOL_BYTES];
  __bf16* sEgoIn = reinterpret_cast<__bf16*>(pool + P_EGOIN);
  __bf16* sEgoH1 = reinterpret_cast<__bf16*>(pool + P_EGOH1);
  __bf16* sEgoH2 = reinterpret_cast<__bf16*>(pool + P_EGOH2);
  __bf16* sAdoIn = reinterpret_cast<__bf16*>(pool + P_ADOIN);
  __bf16* sAdo2  = reinterpret_cast<__bf16*>(pool);
  __bf16* sProj  = reinterpret_cast<__bf16*>(pool + P_PROJIN);
  float*  sObsF  = reinterpret_cast<float*>(pool + P_OBSRAW);
  float*  sOutF  = reinterpret_cast<float*>(pool + P_OUTF);

  // ---- phase 1: coalesced obs -> LDS fp32 + NT passthrough out[:, :48]
  {
    const f32x4* o4 = reinterpret_cast<const f32x4*>(obs);
    for (int idx = tid; idx < 672; idx += 256) {   // 16 rows x 42 f32x4
      int row = idx / 42, c4 = idx % 42;
      f32x4 v = o4[(size_t)(b0+row)*42 + c4];
      *reinterpret_cast<f32x4*>(sObsF + row*168 + c4*4) = v;
      if (c4 < 12)
        __builtin_nontemporal_store(v,
            reinterpret_cast<f32x4*>(out + (size_t)(b0+row)*112 + c4*4));
    }
  }
  __syncthreads();

  // ---- phase 2: build bf16 inputs from LDS fp32
  {
    if (tid < 192) {            // ego: 16 rows x 12 f32x4
      int row = tid / 12, c4 = tid % 12;
      f32x4 v = *reinterpret_cast<const f32x4*>(sObsF + row*168 + c4*4);
      bf16x4 bv = { (__bf16)v[0], (__bf16)v[1], (__bf16)v[2], (__bf16)v[3] };
      int off = (row*128 + c4*8) ^ ((row&7)<<4);
      *reinterpret_cast<bf16x4*>(reinterpret_cast<char*>(sEgoIn) + off) = bv;
    } else {                    // ego zero pad cols 48..63
      int t = tid - 192;        // 0..63
      int row = t >> 2, ch = t & 3;
      bf16x4 z = {};
      int off = (row*128 + 96 + ch*8) ^ ((row&7)<<4);
      *reinterpret_cast<bf16x4*>(reinterpret_cast<char*>(sEgoIn) + off) = z;
    }
    if (tid < 240) {            // ado gather: 80 lds rows x 3 chunks of 8
      int ldsrow = tid / 3, p = tid % 3;
      int n = ldsrow >> 4, r = ldsrow & 15;
      const float* orow = sObsF + r*168 + 48;
      bf16x8 v;
      #pragma unroll
      for (int j = 0; j < 8; ++j) v[j] = (__bf16)orow[(p*8+j)*5 + n];
      int off = (ldsrow*64 + p*16) ^ ((ldsrow&7)<<4);
      *reinterpret_cast<bf16x8*>(reinterpret_cast<char*>(sAdoIn) + off) = v;
    }
    if (tid < 80) {             // cols 24..31: teamid + zero pad
      int n = tid >> 4;
      bf16x8 v = {};
      v[0] = (__bf16)((n >= 2) ? 1.0f : 0.0f);   // team_ids[1:6] = 0,0,1,1,1
      int off = (tid*64 + 48) ^ ((tid&7)<<4);
      *reinterpret_cast<bf16x8*>(reinterpret_cast<char*>(sAdoIn) + off) = v;
    }
  }
  __syncthreads();

  // ---- phase 3: ego0 (EgoIn -> EgoH1)
  gemm4<64, 1, false>(sEgoIn, 0, sEgoH1, 0, ws + OFF_EGO0, eb0, w, lr, lg);
  __syncthreads();

  // ---- phase 4: ego1 (EgoH1 -> EgoH2)
  gemm4<256, 1, false>(sEgoH1, 0, sEgoH2, 0, ws + OFF_EGO1, eb1, w, lr, lg);
  __syncthreads();

  // ---- phase 5: sel (EgoH2 -> slct[4] regs, 1/8 folded). BEFORE ado0 so
  // EgoH2 is dead when ado0 overwrites rows 42-57.
  f32x4 slct[4];
  {
    const __bf16* WT = ws + OFF_SEL;
    #pragma unroll
    for (int pair = 0; pair < 2; ++pair) {
      f32x4 sacc[2];
      sacc[0] = f32x4{0.f,0.f,0.f,0.f};
      sacc[1] = f32x4{0.f,0.f,0.f,0.f};
      #pragma unroll
      for (int kb = 0; kb < 8; ++kb) {
        bf16x8 af = lds_loadA(sEgoH2, lr, kb*64 + lg*16, 512);
        #pragma unroll
        for (int c2 = 0; c2 < 2; ++c2) {
          const int col = w*64 + (pair*2 + c2)*16 + lr;
          bf16x8 bfr = *reinterpret_cast<const bf16x8*>(WT + col*256 + kb*32 + lg*8);
          sacc[c2] = __builtin_amdgcn_mfma_f32_16x16x32_bf16(af, bfr, sacc[c2], 0, 0, 0);
        }
      }
      slct[pair*2 + 0] = sacc[0] * 0.125f;
      slct[pair*2 + 1] = sacc[1] * 0.125f;
    }
  }
  __syncthreads();

  // ---- phase 6: ado0 (AdoIn -> sAdo2 rows 0..79), K=32: af[5] held in regs
  // across both ct-pairs; single SYNCW barrier (all LDS reads precede it).
  {
    const __bf16* WT = ws + OFF_ADO0;
    bf16x8 af[5];
    #pragma unroll
    for (int n = 0; n < 5; ++n)
      af[n] = lds_loadA(sAdoIn, n*16 + lr, lg*16, 64);
    f32x4 acc[5][2];
    #pragma unroll
    for (int n = 0; n < 5; ++n) {
      acc[n][0] = f32x4{0.f,0.f,0.f,0.f};
      acc[n][1] = f32x4{0.f,0.f,0.f,0.f};
    }
    #pragma unroll
    for (int c2 = 0; c2 < 2; ++c2) {
      const int col = w*64 + c2*16 + lr;
      bf16x8 bfr = *reinterpret_cast<const bf16x8*>(WT + col*32 + lg*8);
      #pragma unroll
      for (int n = 0; n < 5; ++n)
        acc[n][c2] = __builtin_amdgcn_mfma_f32_16x16x32_bf16(af[n], bfr, acc[n][c2], 0, 0, 0);
    }
    __syncthreads();   // all waves' AdoIn reads done; writes may begin
    #pragma unroll
    for (int c2 = 0; c2 < 2; ++c2) {
      const int col = w*64 + c2*16 + lr;
      const float bv = ab0[col];
      #pragma unroll
      for (int n = 0; n < 5; ++n)
        #pragma unroll
        for (int e = 0; e < 4; ++e) {
          float x = acc[n][c2][e] + bv;
          x = x > 0.f ? x : 0.01f * x;
          lds_store_bf16(sAdo2, n*16 + lg*4 + e, col, (__bf16)x);
        }
    }
    // ct-pair 1: register-only reads (af held), no barrier needed
    #pragma unroll
    for (int n = 0; n < 5; ++n) {
      acc[n][0] = f32x4{0.f,0.f,0.f,0.f};
      acc[n][1] = f32x4{0.f,0.f,0.f,0.f};
    }
    #pragma unroll
    for (int c2 = 0; c2 < 2; ++c2) {
      const int col = w*64 + (2 + c2)*16 + lr;
      bf16x8 bfr = *reinterpret_cast<const bf16x8*>(WT + col*32 + lg*8);
      #pragma unroll
      for (int n = 0; n < 5; ++n)
        acc[n][c2] = __builtin_amdgcn_mfma_f32_16x16x32_bf16(af[n], bfr, acc[n][c2], 0, 0, 0);
    }
    #pragma unroll
    for (int c2 = 0; c2 < 2; ++c2) {
      const int col = w*64 + (2 + c2)*16 + lr;
      const float bv = ab0[col];
      #pragma unroll
      for (int n = 0; n < 5; ++n)
        #pragma unroll
        for (int e = 0; e < 4; ++e) {
          float x = acc[n][c2][e] + bv;
          x = x > 0.f ? x : 0.01f * x;
          lds_store_bf16(sAdo2, n*16 + lg*4 + e, col, (__bf16)x);
        }
    }
  }
  __syncthreads();

  // ---- phase 7: ado1 IN-PLACE, two pieces (rows 0-47, rows 48-79).
  gemm4<256, 3, true>(sAdo2, 0,  sAdo2, 0,  ws + OFF_ADO1, ab1, w, lr, lg);
  gemm4<256, 2, true>(sAdo2, 48, sAdo2, 48, ws + OFF_ADO1, ab1, w, lr, lg);
  __syncthreads();

  // ---- phase 8: key -> wave-internal softmax -> lat. Agent groups (3+2)
  // cap simultaneous accumulators at 24 regs + af 12.
  f32x4 part[5];
  {
    const __bf16* WK = ws + OFF_KEY;
    #pragma unroll
    for (int n = 0; n < 5; ++n) part[n] = f32x4{0.f,0.f,0.f,0.f};
    #pragma unroll
    for (int pair = 0; pair < 2; ++pair) {
      {
        f32x4 kacc[3][2];
        attn_group<3>(sAdo2, WK, 0, pair, w, lr, lg, kacc);
        #pragma unroll
        for (int n = 0; n < 3; ++n)
          part[n] += kacc[n][0]*slct[pair*2] + kacc[n][1]*slct[pair*2+1];
      }
      {
        f32x4 kacc[2][2];
        attn_group<2>(sAdo2, WK, 3, pair, w, lr, lg, kacc);
        #pragma unroll
        for (int n = 0; n < 2; ++n)
          part[3+n] += kacc[n][0]*slct[pair*2] + kacc[n][1]*slct[pair*2+1];
      }
    }
  }
  // logit reduce over the wave's 16 lr lanes (full d=64 owned by this wave)
  #pragma unroll
  for (int n = 0; n < 5; ++n) {
    #pragma unroll
    for (int m = 1; m < 16; m <<= 1) {
      part[n][0] += __shfl_xor(part[n][0], m);
      part[n][1] += __shfl_xor(part[n][1], m);
      part[n][2] += __shfl_xor(part[n][2], m);
      part[n][3] += __shfl_xor(part[n][3], m);
    }
  }
  // exact softmax over 5 agents, in-lane (reuses part[] as p[])
  {
    f32x4 mx = part[0];
    #pragma unroll
    for (int n = 1; n < 5; ++n)
      #pragma unroll
      for (int e = 0; e < 4; ++e) mx[e] = fmaxf(mx[e], part[n][e]);
    f32x4 s = f32x4{0.f,0.f,0.f,0.f};
    #pragma unroll
    for (int n = 0; n < 5; ++n) {
      #pragma unroll
      for (int e = 0; e < 4; ++e) part[n][e] = __expf(part[n][e] - mx[e]);
      s += part[n];
    }
    f32x4 inv;
    #pragma unroll
    for (int e = 0; e < 4; ++e) inv[e] = 1.0f / s[e];
    #pragma unroll
    for (int n = 0; n < 5; ++n) part[n] *= inv;
  }
  // lat pass + weighted aggregation, same agent grouping
  f32x4 agg[4];
  #pragma unroll
  for (int ct = 0; ct < 4; ++ct) agg[ct] = f32x4{0.f,0.f,0.f,0.f};
  {
    const __bf16* WL = ws + OFF_LAT;
    #pragma unroll
    for (int pair = 0; pair < 2; ++pair) {
      #pragma unroll
      for (int c2p = 0; c2p < 2; ++c2p) { /* placeholder to keep shape flat */ }
      {
        f32x4 lacc[3][2];
        attn_group<3>(sAdo2, WL, 0, pair, w, lr, lg, lacc);
        #pragma unroll
        for (int c2 = 0; c2 < 2; ++c2) {
          const int ct = pair*2 + c2;
          const float lb = latb[w*64 + ct*16 + lr];
          #pragma unroll
          for (int n = 0; n < 3; ++n)
            #pragma unroll
            for (int e = 0; e < 4; ++e) {
              float x = lacc[n][c2][e] + lb;
              x = x > 0.f ? x : 0.01f * x;
              agg[ct][e] += part[n][e] * x;
            }
        }
      }
      {
        f32x4 lacc[2][2];
        attn_group<2>(sAdo2, WL, 3, pair, w, lr, lg, lacc);
        #pragma unroll
        for (int c2 = 0; c2 < 2; ++c2) {
          const int ct = pair*2 + c2;
          const float lb = latb[w*64 + ct*16 + lr];
          #pragma unroll
          for (int n = 0; n < 2; ++n)
            #pragma unroll
            for (int e = 0; e < 4; ++e) {
              float x = lacc[n][c2][e] + lb;
              x = x > 0.f ? x : 0.01f * x;
              agg[ct][e] += part[3+n][e] * x;
            }
        }
      }
    }
  }
  __syncthreads();   // all waves' sAdo2 reads done; sProj (rows 0-15) writes OK
  #pragma unroll
  for (int ct = 0; ct < 4; ++ct)
    #pragma unroll
    for (int e = 0; e < 4; ++e)
      lds_store_bf16(sProj, lg*4 + e, w*64 + ct*16 + lr, (__bf16)agg[ct][e]);
  __syncthreads();

  // ---- phase 9: proj (16x256)@(256x64); wave w -> cols w*16..w*16+15
  {
    const __bf16* WT = ws + OFF_PROJ;
    f32x4 pacc = f32x4{0.f,0.f,0.f,0.f};
    #pragma unroll
    for (int kb = 0; kb < 8; ++kb) {
      bf16x8 af = lds_loadA(sProj, lr, kb*64 + lg*16, 512);
      bf16x8 bfr = *reinterpret_cast<const bf16x8*>(WT + (w*16+lr)*256 + kb*32 + lg*8);
      pacc = __builtin_amdgcn_mfma_f32_16x16x32_bf16(af, bfr, pacc, 0, 0, 0);
    }
    const float pb = projb[w*16 + lr];
    #pragma unroll
    for (int e = 0; e < 4; ++e)
      sOutF[(lg*4 + e)*64 + w*16 + lr] = pacc[e] + pb;   // rows 16-23: disjoint
  }
  __syncthreads();

  // ---- phase 10: coalesced NT float4 writes of out[:, 48:112]
  {
    int row = tid >> 4, q = tid & 15;
    f32x4 v = *reinterpret_cast<const f32x4*>(sOutF + row*64 + q*4);
    __builtin_nontemporal_store(v,
        reinterpret_cast<f32x4*>(out + (size_t)(b0+row)*112 + 48 + q*4));
  }
}

extern "C" void kernel_launch(void* const* d_in, const int* in_sizes, int n_in,
                              void* d_out, int out_size, void* d_ws, size_t ws_size,
                              hipStream_t stream) {
  const float* obs   = (const float*)d_in[0];
  const float* ew0   = (const float*)d_in[1];
  const float* eb0   = (const float*)d_in[2];
  const float* ew1   = (const float*)d_in[3];
  const float* eb1   = (const float*)d_in[4];
  const float* aw0   = (const float*)d_in[5];
  const float* ab0   = (const float*)d_in[6];
  const float* aw1   = (const float*)d_in[7];
  const float* ab1   = (const float*)d_in[8];
  const float* keyw  = (const float*)d_in[9];
  const float* selw  = (const float*)d_in[10];
  const float* latw  = (const float*)d_in[11];
  const float* latb  = (const float*)d_in[12];
  const float* projw = (const float*)d_in[13];
  const float* projb = (const float*)d_in[14];
  __bf16* ws = (__bf16*)d_ws;
  float* out = (float*)d_out;

  prep_weights<<<dim3((WS_ELEMS + 255)/256), dim3(256), 0, stream>>>(
      ew0, ew1, aw0, aw1, keyw, selw, latw, projw, ws);
  fused_kernel<<<dim3(65536/16), dim3(256), 0, stream>>>(
      obs, eb0, eb1, ab0, ab1, latb, projb, ws, out);
}

// Round 9
// 457.917 us; speedup vs baseline: 3.4748x; 3.4748x over previous
//
#include <hip/hip_runtime.h>
#include <hip/hip_bf16.h>

// EncoderAttention4 v10: v3 (clean 457us base) + nontemporal obs loads.
// B=65536, NEGO=48, NADO=24, NADOAG=5, E=256, H=4, AD=64. Out: (B,112) fp32.
//
// v8/v9 post-mortem: gfx950 splits the unified RF ~64 VGPR + 64 AGPR at the
// 4-waves/EU target; MFMA accs take the AGPR half, ALL long-lived VALU state
// must fit in 64 VGPRs. v3's column-split shape fits (steady-state traffic
// 60MB = ideal); wave-per-head shapes spill (GBs of scratch). Revert to v3.
// v3's remaining 70% stall arithmetic: ~76 serialized load->MFMA steps per
// block only explain the measured 1.1M cy/CU if B-fragment loads cost
// ~900cy = L3, not L2 — the obs/out streams (73MB/dispatch) keep flushing
// the 737KB weight ws out of each XCD's 4MB L2. v10: mark the obs read
// stream nontemporal (out is already NT) so L2 retains ws.

typedef __bf16 bf16x8 __attribute__((ext_vector_type(8)));
typedef __bf16 bf16x4 __attribute__((ext_vector_type(4)));
typedef float  f32x4  __attribute__((ext_vector_type(4)));

// Workspace layout (bf16 elements), unchanged.
#define OFF_EGO0 0        // [256][64]  (K=48 padded to 64)
#define OFF_EGO1 16384    // [256][256]
#define OFF_ADO0 81920    // [256][32]  (K=25 padded to 32)
#define OFF_ADO1 90112    // [256][256]
#define OFF_SEL  155648   // [256][256] col c -> head c>>6, d c&63
#define OFF_KEY  221184
#define OFF_LAT  286720
#define OFF_PROJ 352256   // [64][256]
#define WS_ELEMS 368640

__global__ __launch_bounds__(256) void prep_weights(
    const float* __restrict__ ew0, const float* __restrict__ ew1,
    const float* __restrict__ aw0, const float* __restrict__ aw1,
    const float* __restrict__ keyw, const float* __restrict__ selw,
    const float* __restrict__ latw, const float* __restrict__ projw,
    __bf16* __restrict__ ws)
{
  int i = blockIdx.x * 256 + threadIdx.x;
  if (i >= WS_ELEMS) return;
  float v;
  if (i < OFF_EGO1)      { int j=i;          int c=j>>6, k=j&63;  v = (k<48) ? ew0[k*256+c] : 0.f; }
  else if (i < OFF_ADO0) { int j=i-OFF_EGO1; int c=j>>8, k=j&255; v = ew1[k*256+c]; }
  else if (i < OFF_ADO1) { int j=i-OFF_ADO0; int c=j>>5, k=j&31;  v = (k<25) ? aw0[k*256+c] : 0.f; }
  else if (i < OFF_SEL)  { int j=i-OFF_ADO1; int c=j>>8, k=j&255; v = aw1[k*256+c]; }
  else if (i < OFF_KEY)  { int j=i-OFF_SEL;  int c=j>>8, k=j&255; v = selw[(c>>6)*16384 + k*64 + (c&63)]; }
  else if (i < OFF_LAT)  { int j=i-OFF_KEY;  int c=j>>8, k=j&255; v = keyw[(c>>6)*16384 + k*64 + (c&63)]; }
  else if (i < OFF_PROJ) { int j=i-OFF_LAT;  int c=j>>8, k=j&255; v = latw[(c>>6)*16384 + k*64 + (c&63)]; }
  else                   { int j=i-OFF_PROJ; int c=j>>8, k=j&255; v = projw[k*64+c]; }
  ws[i] = (__bf16)v;
}

// XOR-swizzled LDS accessors. byte ^= (row&7)<<4.
__device__ __forceinline__ bf16x8 lds_loadA(const __bf16* base, int row, int kByte, int rowBytes) {
  int off = (row * rowBytes + kByte) ^ ((row & 7) << 4);
  return *reinterpret_cast<const bf16x8*>(reinterpret_cast<const char*>(base) + off);
}
__device__ __forceinline__ void lds_store_bf16(__bf16* base, int row, int col, __bf16 v) {
  int off = (row * 512 + col * 2) ^ ((row & 7) << 4);  // 256-col tiles only
  *reinterpret_cast<__bf16*>(reinterpret_cast<char*>(base) + off) = v;
}

// LDS pool (bytes). Aliased regions with phase-disjoint lifetimes:
//   P_ADO2  [0,40960)      : ado activations, 80x512 swz (written ph4/ph6)
//     P_EGOIN [0,2048)     : ego input 16x128 swz   (dead after ph2)
//     P_EGOH1 [2048,10240) : ego hidden1 16x512 swz (dead after ph3)
//     P_ADOIN [24576,29696): ado input 80x64 swz    (dead after ph5)
//   P_EGOH2 [40960,49152)  : ego hidden2 16x512 swz (dead after ph4 'sel')
//     P_PROJIN (same addr) : proj input 16x512 swz  (written ph7)
//   P_H1    [49152,73728)  : ado hidden1 half, 48x512 swz (dead after ph6)
//     P_OBSRAW (same addr) : raw fp32 obs 16x168    (dead after ph1b)
//   P_OUT   [73728,77824)  : logit exchange (ph7) then proj fp32 out (ph8)
#define P_ADO2   0
#define P_EGOIN  0
#define P_EGOH1  2048
#define P_ADOIN  24576
#define P_EGOH2  40960
#define P_PROJIN 40960
#define P_H1     49152
#define P_OBSRAW 49152
#define P_OUT    73728
#define POOL_BYTES 77824   // 76KB -> 2 blocks/CU (152KB of 160KB)

// C(out 16R rows x 32 cols/wave) = act(A @ WT^T + bias). Column-split:
// wave w owns cols w*32 + c2*16 + lr. Each B fragment read once per block.
template<int KP, int R, bool ACT>
__device__ __forceinline__ void gemm_block(const __bf16* __restrict__ sA, int aRow0,
                                           __bf16* __restrict__ sC, int cRow0,
                                           const __bf16* __restrict__ WT,
                                           const float* __restrict__ bias,
                                           int w, int lr, int lg)
{
  constexpr int NKB = KP / 32;
  f32x4 acc[R][2];
  #pragma unroll
  for (int t = 0; t < R; ++t) {
    acc[t][0] = f32x4{0.f,0.f,0.f,0.f};
    acc[t][1] = f32x4{0.f,0.f,0.f,0.f};
  }
  #pragma unroll
  for (int kb = 0; kb < NKB; ++kb) {
    bf16x8 af[R];
    #pragma unroll
    for (int t = 0; t < R; ++t)
      af[t] = lds_loadA(sA, aRow0 + t*16 + lr, kb*64 + lg*16, KP*2);
    #pragma unroll
    for (int c2 = 0; c2 < 2; ++c2) {
      const int col = w*32 + c2*16 + lr;
      bf16x8 bfr = *reinterpret_cast<const bf16x8*>(WT + col*KP + kb*32 + lg*8);
      #pragma unroll
      for (int t = 0; t < R; ++t)
        acc[t][c2] = __builtin_amdgcn_mfma_f32_16x16x32_bf16(af[t], bfr, acc[t][c2], 0, 0, 0);
    }
  }
  #pragma unroll
  for (int c2 = 0; c2 < 2; ++c2) {
    const int col = w*32 + c2*16 + lr;
    const float bv = bias[col];
    #pragma unroll
    for (int t = 0; t < R; ++t) {
      #pragma unroll
      for (int e = 0; e < 4; ++e) {
        float x = acc[t][c2][e] + bv;
        if (ACT) x = x > 0.f ? x : 0.01f * x;
        lds_store_bf16(sC, cRow0 + t*16 + lg*4 + e, col, (__bf16)x);
      }
    }
  }
}

__global__ __launch_bounds__(512, 4) void fused_kernel(
    const float* __restrict__ obs,
    const float* __restrict__ eb0, const float* __restrict__ eb1,
    const float* __restrict__ ab0, const float* __restrict__ ab1,
    const float* __restrict__ latb, const float* __restrict__ projb,
    const __bf16* __restrict__ ws,
    float* __restrict__ out)
{
  const int tid = threadIdx.x;
  const int w  = tid >> 6;   // 8 waves
  const int l  = tid & 63;
  const int lr = l & 15;
  const int lg = l >> 4;
  const int b0 = blockIdx.x * 16;

  __shared__ __align__(16) char pool[POOL_BYTES];
  __bf16* sEgoIn = reinterpret_cast<__bf16*>(pool + P_EGOIN);
  __bf16* sEgoH1 = reinterpret_cast<__bf16*>(pool + P_EGOH1);
  __bf16* sAdoIn = reinterpret_cast<__bf16*>(pool + P_ADOIN);
  __bf16* sEgoH2 = reinterpret_cast<__bf16*>(pool + P_EGOH2);
  __bf16* sProj  = reinterpret_cast<__bf16*>(pool + P_PROJIN);
  __bf16* sAdo2  = reinterpret_cast<__bf16*>(pool + P_ADO2);
  __bf16* sH1    = reinterpret_cast<__bf16*>(pool + P_H1);
  float*  sObsF  = reinterpret_cast<float*>(pool + P_OBSRAW);
  float*  sLogF  = reinterpret_cast<float*>(pool + P_OUT);
  float*  sOutF  = reinterpret_cast<float*>(pool + P_OUT);

  // ---- phase 1a: NONTEMPORAL coalesced obs -> LDS (fp32) + NT passthrough.
  // nt on the 44MB obs read stream keeps it from flushing the 737KB weight
  // workspace out of L2 (the out stream is already NT).
  {
    const f32x4* o4 = reinterpret_cast<const f32x4*>(obs);
    #pragma unroll
    for (int idx = tid; idx < 672; idx += 512) {   // 16 rows x 42 f32x4
      int row = idx / 42, c4 = idx % 42;
      f32x4 v = __builtin_nontemporal_load(o4 + (size_t)(b0+row)*42 + c4);
      *reinterpret_cast<f32x4*>(sObsF + row*168 + c4*4) = v;
      if (c4 < 12)
        __builtin_nontemporal_store(v,
            reinterpret_cast<f32x4*>(out + (size_t)(b0+row)*112 + c4*4));
    }
  }
  __syncthreads();

  // ---- phase 1b: build bf16 inputs from LDS fp32
  {
    if (tid < 192) {            // ego: 16 rows x 12 f32x4
      int row = tid / 12, c4 = tid % 12;
      f32x4 v = *reinterpret_cast<const f32x4*>(sObsF + row*168 + c4*4);
      bf16x4 bv = { (__bf16)v[0], (__bf16)v[1], (__bf16)v[2], (__bf16)v[3] };
      int off = (row*128 + c4*8) ^ ((row&7)<<4);
      *reinterpret_cast<bf16x4*>(reinterpret_cast<char*>(sEgoIn) + off) = bv;
    } else if (tid < 256) {     // ego zero pad cols 48..63
      int t = tid - 192;
      int row = t >> 2, ch = t & 3;
      bf16x4 z = {};
      int off = (row*128 + 96 + ch*8) ^ ((row&7)<<4);
      *reinterpret_cast<bf16x4*>(reinterpret_cast<char*>(sEgoIn) + off) = z;
    }
    if (tid >= 256 && tid < 496) {  // ado gather: 80 lds rows x 3 chunks of 8
      int t = tid - 256;
      int ldsrow = t / 3, p = t % 3;
      int n = ldsrow >> 4, r = ldsrow & 15;
      const float* orow = sObsF + r*168 + 48;
      bf16x8 v;
      #pragma unroll
      for (int j = 0; j < 8; ++j) v[j] = (__bf16)orow[(p*8+j)*5 + n];
      int off = (ldsrow*64 + p*16) ^ ((ldsrow&7)<<4);
      *reinterpret_cast<bf16x8*>(reinterpret_cast<char*>(sAdoIn) + off) = v;
    }
    if (tid >= 432) {               // cols 24..31: teamid + zero pad
      int t = tid - 432;            // 0..79
      int n = t >> 4;
      bf16x8 v = {};
      v[0] = (__bf16)((n >= 2) ? 1.0f : 0.0f);   // team_ids[1:6] = 0,0,1,1,1
      int off = (t*64 + 48) ^ ((t&7)<<4);
      *reinterpret_cast<bf16x8*>(reinterpret_cast<char*>(sAdoIn) + off) = v;
    }
  }
  __syncthreads();

  // ---- phase 2: ego0 + ado0 (agents 0..2 -> sH1 rows 0..47)
  gemm_block<64, 1, true>(sEgoIn, 0, sEgoH1, 0, ws + OFF_EGO0, eb0, w, lr, lg);
  gemm_block<32, 3, true>(sAdoIn, 0, sH1,    0, ws + OFF_ADO0, ab0, w, lr, lg);
  __syncthreads();

  // ---- phase 3: ego1
  gemm_block<256, 1, true>(sEgoH1, 0, sEgoH2, 0, ws + OFF_EGO1, eb1, w, lr, lg);
  __syncthreads();

  // ---- phase 4: sel (regs, 1/8 folded) + ado1 agents 0..2 -> sAdo2 rows 0..47
  f32x4 slct[2];
  {
    const __bf16* WT = ws + OFF_SEL;
    slct[0] = f32x4{0.f,0.f,0.f,0.f};
    slct[1] = f32x4{0.f,0.f,0.f,0.f};
    #pragma unroll
    for (int kb = 0; kb < 8; ++kb) {
      bf16x8 af = lds_loadA(sEgoH2, lr, kb*64 + lg*16, 512);
      #pragma unroll
      for (int c2 = 0; c2 < 2; ++c2) {
        bf16x8 bfr = *reinterpret_cast<const bf16x8*>(WT + (w*32+c2*16+lr)*256 + kb*32 + lg*8);
        slct[c2] = __builtin_amdgcn_mfma_f32_16x16x32_bf16(af, bfr, slct[c2], 0, 0, 0);
      }
    }
    slct[0] *= 0.125f;   // fold 1/sqrt(AD) into slct
    slct[1] *= 0.125f;
  }
  gemm_block<256, 3, true>(sH1, 0, sAdo2, 0, ws + OFF_ADO1, ab1, w, lr, lg);
  __syncthreads();

  // ---- phase 5: ado0 agents 3..4 -> sH1 rows 0..31
  gemm_block<32, 2, true>(sAdoIn, 48, sH1, 0, ws + OFF_ADO0, ab0, w, lr, lg);
  __syncthreads();

  // ---- phase 6: ado1 agents 3..4 -> sAdo2 rows 48..79
  gemm_block<256, 2, true>(sH1, 0, sAdo2, 48, ws + OFF_ADO1, ab1, w, lr, lg);
  __syncthreads();

  // ---- phase 7: key pass -> pair-wise logit exchange -> softmax -> lat pass
  f32x4 part[5];
  #pragma unroll
  for (int n = 0; n < 5; ++n) part[n] = f32x4{0.f,0.f,0.f,0.f};
  {
    const __bf16* WK = ws + OFF_KEY;
    #pragma unroll
    for (int c2 = 0; c2 < 2; ++c2) {
      f32x4 kacc[5];
      #pragma unroll
      for (int n = 0; n < 5; ++n) kacc[n] = f32x4{0.f,0.f,0.f,0.f};
      const int col = w*32 + c2*16 + lr;
      #pragma unroll
      for (int kb = 0; kb < 8; ++kb) {
        bf16x8 af[5];
        #pragma unroll
        for (int n = 0; n < 5; ++n)
          af[n] = lds_loadA(sAdo2, n*16 + lr, kb*64 + lg*16, 512);
        bf16x8 bk = *reinterpret_cast<const bf16x8*>(WK + col*256 + kb*32 + lg*8);
        #pragma unroll
        for (int n = 0; n < 5; ++n)
          kacc[n] = __builtin_amdgcn_mfma_f32_16x16x32_bf16(af[n], bk, kacc[n], 0, 0, 0);
      }
      #pragma unroll
      for (int n = 0; n < 5; ++n) part[n] += kacc[n] * slct[c2];
    }
  }
  // reduce over lr lanes (sum over this wave's 32 d-dims)
  #pragma unroll
  for (int n = 0; n < 5; ++n) {
    #pragma unroll
    for (int m = 1; m < 16; m <<= 1) {
      part[n][0] += __shfl_xor(part[n][0], m);
      part[n][1] += __shfl_xor(part[n][1], m);
      part[n][2] += __shfl_xor(part[n][2], m);
      part[n][3] += __shfl_xor(part[n][3], m);
    }
  }
  // publish wave partials: sLogF[w][n][row] (f32x4 per (w,n,lg))
  #pragma unroll
  for (int n = 0; n < 5; ++n)
    if (lr == n)
      *reinterpret_cast<f32x4*>(sLogF + (w*5 + n)*16 + lg*4) = part[n];
  __syncthreads();
  // full logits = this wave's partial + partner wave's partial; exact softmax
  f32x4 p[5];
  {
    f32x4 lt[5];
    #pragma unroll
    for (int n = 0; n < 5; ++n)
      lt[n] = *reinterpret_cast<const f32x4*>(sLogF + (w*5 + n)*16 + lg*4)
            + *reinterpret_cast<const f32x4*>(sLogF + ((w^1)*5 + n)*16 + lg*4);
    f32x4 mx = lt[0];
    #pragma unroll
    for (int n = 1; n < 5; ++n)
      #pragma unroll
      for (int e = 0; e < 4; ++e) mx[e] = fmaxf(mx[e], lt[n][e]);
    f32x4 s = f32x4{0.f,0.f,0.f,0.f};
    #pragma unroll
    for (int n = 0; n < 5; ++n) {
      #pragma unroll
      for (int e = 0; e < 4; ++e) p[n][e] = __expf(lt[n][e] - mx[e]);
      s += p[n];
    }
    f32x4 inv;
    #pragma unroll
    for (int e = 0; e < 4; ++e) inv[e] = 1.0f / s[e];
    #pragma unroll
    for (int n = 0; n < 5; ++n) p[n] *= inv;
  }
  // lat pass: weighted aggregation in registers
  f32x4 agg[2];
  agg[0] = f32x4{0.f,0.f,0.f,0.f};
  agg[1] = f32x4{0.f,0.f,0.f,0.f};
  {
    const __bf16* WL = ws + OFF_LAT;
    #pragma unroll
    for (int c2 = 0; c2 < 2; ++c2) {
      f32x4 lacc[5];
      #pragma unroll
      for (int n = 0; n < 5; ++n) lacc[n] = f32x4{0.f,0.f,0.f,0.f};
      const int col = w*32 + c2*16 + lr;
      #pragma unroll
      for (int kb = 0; kb < 8; ++kb) {
        bf16x8 af[5];
        #pragma unroll
        for (int n = 0; n < 5; ++n)
          af[n] = lds_loadA(sAdo2, n*16 + lr, kb*64 + lg*16, 512);
        bf16x8 bl = *reinterpret_cast<const bf16x8*>(WL + col*256 + kb*32 + lg*8);
        #pragma unroll
        for (int n = 0; n < 5; ++n)
          lacc[n] = __builtin_amdgcn_mfma_f32_16x16x32_bf16(af[n], bl, lacc[n], 0, 0, 0);
      }
      const float lb = latb[col];
      #pragma unroll
      for (int n = 0; n < 5; ++n) {
        #pragma unroll
        for (int e = 0; e < 4; ++e) {
          float x = lacc[n][e] + lb;
          x = x > 0.f ? x : 0.01f * x;
          agg[c2][e] += p[n][e] * x;
        }
      }
    }
  }
  // agg -> sProj (proj input, bf16 swz). Overwrites sEgoH2 (dead).
  #pragma unroll
  for (int c2 = 0; c2 < 2; ++c2)
    #pragma unroll
    for (int e = 0; e < 4; ++e)
      lds_store_bf16(sProj, lg*4 + e, w*32 + c2*16 + lr, (__bf16)agg[c2][e]);
  __syncthreads();

  // ---- phase 8: proj (16x256)@(256x64); waves 0..3 -> cols w*16..w*16+15
  if (w < 4) {
    const __bf16* WT = ws + OFF_PROJ;
    f32x4 pacc = f32x4{0.f,0.f,0.f,0.f};
    #pragma unroll
    for (int kb = 0; kb < 8; ++kb) {
      bf16x8 af = lds_loadA(sProj, lr, kb*64 + lg*16, 512);
      bf16x8 bfr = *reinterpret_cast<const bf16x8*>(WT + (w*16+lr)*256 + kb*32 + lg*8);
      pacc = __builtin_amdgcn_mfma_f32_16x16x32_bf16(af, bfr, pacc, 0, 0, 0);
    }
    const float pb = projb[w*16 + lr];
    #pragma unroll
    for (int e = 0; e < 4; ++e)
      sOutF[(lg*4 + e)*64 + w*16 + lr] = pacc[e] + pb;
  }
  __syncthreads();

  // ---- phase 9: coalesced NT float4 writes of out[:, 48:112]
  if (tid < 256) {
    int row = tid >> 4, q = tid & 15;
    f32x4 v = *reinterpret_cast<const f32x4*>(sOutF + row*64 + q*4);
    __builtin_nontemporal_store(v,
        reinterpret_cast<f32x4*>(out + (size_t)(b0+row)*112 + 48 + q*4));
  }
}

extern "C" void kernel_launch(void* const* d_in, const int* in_sizes, int n_in,
                              void* d_out, int out_size, void* d_ws, size_t ws_size,
                              hipStream_t stream) {
  const float* obs   = (const float*)d_in[0];
  const float* ew0   = (const float*)d_in[1];
  const float* eb0   = (const float*)d_in[2];
  const float* ew1   = (const float*)d_in[3];
  const float* eb1   = (const float*)d_in[4];
  const float* aw0   = (const float*)d_in[5];
  const float* ab0   = (const float*)d_in[6];
  const float* aw1   = (const float*)d_in[7];
  const float* ab1   = (const float*)d_in[8];
  const float* keyw  = (const float*)d_in[9];
  const float* selw  = (const float*)d_in[10];
  const float* latw  = (const float*)d_in[11];
  const float* latb  = (const float*)d_in[12];
  const float* projw = (const float*)d_in[13];
  const float* projb = (const float*)d_in[14];
  __bf16* ws = (__bf16*)d_ws;
  float* out = (float*)d_out;

  prep_weights<<<dim3((WS_ELEMS + 255)/256), dim3(256), 0, stream>>>(
      ew0, ew1, aw0, aw1, keyw, selw, latw, projw, ws);
  fused_kernel<<<dim3(65536/16), dim3(512), 0, stream>>>(
      obs, eb0, eb1, ab0, ab1, latb, projb, ws, out);
}